// Round 3
// baseline (168.552 us; speedup 1.0000x reference)
//
#include <hip/hip_runtime.h>

typedef __attribute__((ext_vector_type(8))) __bf16 bf16x8;
typedef __attribute__((ext_vector_type(4))) __bf16 bf16x4;
typedef __attribute__((ext_vector_type(4))) float f32x4;

__device__ __forceinline__ void async_load16(const void* g, void* l) {
  __builtin_amdgcn_global_load_lds(
      (const __attribute__((address_space(1))) void*)g,
      (__attribute__((address_space(3))) void*)l, 16, 0, 0);
}

// ---------------- fp32 -> bf16 convert (vectorized) ----------------
__global__ void cvt_f32_bf16(const float* __restrict__ in,
                             __bf16* __restrict__ out, int n4) {
  int i = blockIdx.x * blockDim.x + threadIdx.x;
  int stride = gridDim.x * blockDim.x;
  for (; i < n4; i += stride) {
    float4 v = ((const float4*)in)[i];
    bf16x4 o;
    o[0] = (__bf16)v.x; o[1] = (__bf16)v.y; o[2] = (__bf16)v.z; o[3] = (__bf16)v.w;
    ((bf16x4*)out)[i] = o;
  }
}

// ---------------- C = (A @ Bm^T + bias) [*scale] ----------------
// MODE 0: fp32 out, row stride N.
// MODE 1 (QKV): cols<512 -> qk bf16 (scaled 0.125); cols 512..1023 -> qk bf16;
//               cols>=1024 -> vT[b][h][d][k] transposed bf16 (k = row within batch).
template <int MODE>
__global__ __launch_bounds__(256) void gemm_bt(
    const __bf16* __restrict__ A,   // [M][K]
    const __bf16* __restrict__ Bm,  // [N][K]
    const float* __restrict__ bias, // [N]
    void* __restrict__ C0,          // MODE0: fp32 [M][N]; MODE1: bf16 qk [M][1024]
    __bf16* __restrict__ vT,        // MODE1: bf16 [B*8][64][1024]
    int M, int N, int K) {
  __shared__ __align__(16) char smem[32768];
  char* lA = smem;
  char* lB = smem + 16384;
  const int t = threadIdx.x;
  const int lane = t & 63;
  const int wid = t >> 6;
  const int wm = wid >> 1, wn = wid & 1;
  const int g = lane >> 4, ln = lane & 15;
  const int m0 = blockIdx.y * 128;
  const int n0 = blockIdx.x * 128;

  const int srow = t >> 3;
  const int sswz = ((t & 7) * 16) ^ ((srow & 7) << 4);
  const size_t KB = (size_t)K * 2;
  const char* gA = (const char*)A + (size_t)m0 * KB;
  const char* gB = (const char*)Bm + (size_t)n0 * KB;

  f32x4 acc[4][4] = {};

  for (int k0 = 0; k0 < K; k0 += 64) {
    __syncthreads();
#pragma unroll
    for (int c = 0; c < 4; ++c) {
      int row = srow + 32 * c;
      async_load16(gA + (size_t)row * KB + k0 * 2 + sswz, lA + c * 4096 + t * 16);
      async_load16(gB + (size_t)row * KB + k0 * 2 + sswz, lB + c * 4096 + t * 16);
    }
    __syncthreads();
#pragma unroll
    for (int ks = 0; ks < 2; ++ks) {
      bf16x8 af[4], bf[4];
#pragma unroll
      for (int i = 0; i < 4; ++i) {
        int ar = wm * 64 + i * 16 + ln;
        int byo = (ks * 64 + g * 16) ^ ((ar & 7) << 4);
        af[i] = *(const bf16x8*)(lA + ar * 128 + byo);
        int br = wn * 64 + i * 16 + ln;
        bf[i] = *(const bf16x8*)(lB + br * 128 + byo);
      }
#pragma unroll
      for (int i = 0; i < 4; ++i)
#pragma unroll
        for (int j = 0; j < 4; ++j)
          acc[i][j] = __builtin_amdgcn_mfma_f32_16x16x32_bf16(af[i], bf[j], acc[i][j], 0, 0, 0);
    }
  }

#pragma unroll
  for (int j = 0; j < 4; ++j) {
    int col = n0 + wn * 64 + j * 16 + ln;
    float bv = bias[col];
    if (MODE == 0) {
#pragma unroll
      for (int i = 0; i < 4; ++i) {
        int row0 = m0 + wm * 64 + i * 16 + g * 4;
#pragma unroll
        for (int r = 0; r < 4; ++r)
          ((float*)C0)[(size_t)(row0 + r) * N + col] = acc[i][j][r] + bv;
      }
    } else if (col < 1024) {  // uniform per block (n0 multiple of 128)
      float scale = (col < 512) ? 0.125f : 1.0f;
#pragma unroll
      for (int i = 0; i < 4; ++i) {
        int row0 = m0 + wm * 64 + i * 16 + g * 4;
#pragma unroll
        for (int r = 0; r < 4; ++r)
          ((__bf16*)C0)[(size_t)(row0 + r) * 1024 + col] = (__bf16)((acc[i][j][r] + bv) * scale);
      }
    } else {  // V columns -> vT[b*8+h][d][k], k-contiguous bf16x4 stores
      int h = (col - 1024) >> 6;
      int d = (col - 1024) & 63;
#pragma unroll
      for (int i = 0; i < 4; ++i) {
        int row0 = m0 + wm * 64 + i * 16 + g * 4;  // 128-tiles never straddle batches
        int b = row0 >> 10;
        bf16x4 pk;
#pragma unroll
        for (int r = 0; r < 4; ++r) pk[r] = (__bf16)(acc[i][j][r] + bv);
        *(bf16x4*)(vT + (((size_t)b * 8 + h) * 64 + d) * 1024 + (row0 & 1023)) = pk;
      }
    }
  }
}

// ---------------- fused flash attention ----------------
// 512 blocks (XCD-swizzled: one batch per XCD), 512 threads = 8 waves = 8 heads.
// QT=16, KT=32. LDS 67.6KB -> 2 blocks/CU (16 waves/CU).
__global__ __launch_bounds__(512, 4) void attn_fused(
    const __bf16* __restrict__ qk,   // [B][N][1024]: q(prescaled)|k
    const __bf16* __restrict__ vT,   // [B*8][64 d][1024 k]
    const float* __restrict__ gbias, // [B][N][N]
    const float* __restrict__ bstr,  // [1]
    __bf16* __restrict__ attn) {     // [B][N][512]
  __shared__ __align__(16) char smem[65536 + 16 * 33 * 4];
  const int t = threadIdx.x;
  const int lane = t & 63;
  const int h = t >> 6;
  const int g = lane >> 4, ln = lane & 15;
  const int wg = ((blockIdx.x & 7) << 6) + (blockIdx.x >> 3);
  const int b = wg >> 6;
  const int q0 = (wg & 63) << 4;

  char* Ks = smem + h * 8192;  // [32 k][128B] XOR-swizzled rows
  char* Ps = Ks;               // alias: P[16 q][64B], overwrites K after QK^T
  char* Vs = Ks + 4096;        // [64 d][64B] XOR-swizzled rows
  float* bias_s = (float*)(smem + 65536);  // [16 q][33]

  const float alpha = 1.f / (1.f + __expf(-bstr[0]));
  const float bscale = 10.f * alpha;
  const f32x4 fzero = {0.f, 0.f, 0.f, 0.f};

  // Q A-frags: row = ln, k-dim = ks*32 + g*8 + j (prescaled by 1/8 in GEMM1)
  bf16x8 qf[2];
#pragma unroll
  for (int ks = 0; ks < 2; ++ks)
    qf[ks] = *(const bf16x8*)(qk + ((size_t)b * 1024 + q0 + ln) * 1024 +
                              h * 64 + ks * 32 + g * 8);

  float m_run[4], l_run[4];
  f32x4 o_acc[4] = {};
#pragma unroll
  for (int r = 0; r < 4; ++r) { m_run[r] = -1e30f; l_run[r] = 0.f; }

  const int krow = lane >> 3;                                // 0..7
  const int ksrc = ((lane & 7) * 16) ^ (krow << 4);
  const int vrow = lane >> 2;                                // 0..15
  const int vsrc = ((lane & 3) * 16) ^ ((vrow & 3) << 4);
  const int kb = t >> 4;                                     // 0..31
  const int qb = t & 15;
  const size_t gb_base = (size_t)b * 1024 * 1024 + q0 + qb;
  float bias_pf = gbias[gb_base + (size_t)kb * 1024];

  const char* qkb = (const char*)qk + (size_t)b * 1024 * 2048;
  const char* vTb = (const char*)vT + (size_t)(b * 8 + h) * 64 * 2048;

  for (int kt = 0; kt < 32; ++kt) {
    const int k0 = kt * 32;
    __syncthreads();  // prev tile's bias_s/P/V reads complete
    bias_s[qb * 33 + kb] = bscale * (1.f / (1.f + __expf(-bias_pf)) - 0.5f);
    // stage K [32 k][128B] and V^T [64 d][64B], swizzled via source permutation
#pragma unroll
    for (int c = 0; c < 4; ++c) {
      async_load16(qkb + (size_t)(k0 + c * 8 + krow) * 2048 + 1024 + h * 128 + ksrc,
                   Ks + c * 1024 + lane * 16);
      async_load16(vTb + (size_t)(c * 16 + vrow) * 2048 + (size_t)k0 * 2 + vsrc,
                   Vs + c * 1024 + lane * 16);
    }
    // prefetch next tile's bias element (HBM latency off critical path)
    int k0n = (kt < 31) ? k0 + 32 : 0;
    bias_pf = gbias[gb_base + (size_t)(k0n + kb) * 1024];
    __syncthreads();  // implicit vmcnt(0): bias_s + K + V visible

    // S = Q K^T  (D: q = 4g + r, key = ni*16 + ln)
    f32x4 s[2];
#pragma unroll
    for (int ni = 0; ni < 2; ++ni) {
      int br = ni * 16 + ln;
      int sw = (br & 7) << 4;
#pragma unroll
      for (int ks = 0; ks < 2; ++ks) {
        bf16x8 kf = *(const bf16x8*)(Ks + br * 128 + ((ks * 64 + g * 16) ^ sw));
        s[ni] = __builtin_amdgcn_mfma_f32_16x16x32_bf16(
            qf[ks], kf, (ks == 0) ? fzero : s[ni], 0, 0, 0);
      }
#pragma unroll
      for (int r = 0; r < 4; ++r)
        s[ni][r] += bias_s[(g * 4 + r) * 33 + br];
    }

    // online softmax (rows spread over the 16 ln-lanes)
#pragma unroll
    for (int r = 0; r < 4; ++r) {
      float tm = fmaxf(s[0][r], s[1][r]);
#pragma unroll
      for (int off = 1; off < 16; off <<= 1)
        tm = fmaxf(tm, __shfl_xor(tm, off, 64));
      float newm = fmaxf(m_run[r], tm);
      float corr = __expf(m_run[r] - newm);
      float p0 = __expf(s[0][r] - newm);
      float p1 = __expf(s[1][r] - newm);
      s[0][r] = p0; s[1][r] = p1;
      float rs = p0 + p1;
#pragma unroll
      for (int off = 1; off < 16; off <<= 1)
        rs += __shfl_xor(rs, off, 64);
      m_run[r] = newm;
      l_run[r] = l_run[r] * corr + rs;
#pragma unroll
      for (int di = 0; di < 4; ++di)
        o_acc[di][r] *= corr;
    }

    // P -> LDS bf16 (swizzled), overwrites K region (wave-local, reads done)
#pragma unroll
    for (int ni = 0; ni < 2; ++ni)
#pragma unroll
      for (int r = 0; r < 4; ++r) {
        int q = g * 4 + r;
        *(__bf16*)(Ps + q * 64 + ((ni * 32 + ln * 2) ^ (((q >> 1) & 3) << 4))) =
            (__bf16)s[ni][r];
      }

    // O += P V : both operands via swizzled ds_read_b128
    bf16x8 pf = *(const bf16x8*)(Ps + ln * 64 + ((g * 16) ^ (((ln >> 1) & 3) << 4)));
#pragma unroll
    for (int di = 0; di < 4; ++di) {
      bf16x8 vf = *(const bf16x8*)(Vs + (di * 16 + ln) * 64 + ((g * 16) ^ ((ln & 3) << 4)));
      o_acc[di] = __builtin_amdgcn_mfma_f32_16x16x32_bf16(pf, vf, o_acc[di], 0, 0, 0);
    }
  }

  // normalize + store (attn[b][q][h*64 + di*16 + ln]); D row = 4g + r
#pragma unroll
  for (int r = 0; r < 4; ++r) {
    float inv = 1.f / l_run[r];
    int q = q0 + g * 4 + r;
#pragma unroll
    for (int di = 0; di < 4; ++di)
      attn[((size_t)b * 1024 + q) * 512 + h * 64 + di * 16 + ln] =
          (__bf16)(o_acc[di][r] * inv);
  }
}

extern "C" void kernel_launch(void* const* d_in, const int* in_sizes, int n_in,
                              void* d_out, int out_size, void* d_ws, size_t ws_size,
                              hipStream_t stream) {
  const float* x     = (const float*)d_in[0];
  const float* gb    = (const float*)d_in[1];
  const float* w_in  = (const float*)d_in[2];
  const float* b_in  = (const float*)d_in[3];
  const float* w_out = (const float*)d_in[4];
  const float* b_out = (const float*)d_in[5];
  const float* bstr  = (const float*)d_in[6];

  char* ws = (char*)d_ws;
  __bf16* qk  = (__bf16*)(ws);                        // 8*1024*1024*2 = 16777216
  __bf16* vT  = (__bf16*)(ws + 16777216);             // 8*8*64*1024*2 = 8388608
  __bf16* xb  = (__bf16*)(ws + 25165824);             // 8388608
  __bf16* w1  = (__bf16*)(ws + 33554432);             // 1572864
  __bf16* w2  = (__bf16*)(ws + 35127296);             // 524288
  __bf16* attn_buf = xb;  // alias: x_bf16 dead after GEMM1

  cvt_f32_bf16<<<2048, 256, 0, stream>>>(x, xb, (8 * 1024 * 512) / 4);
  cvt_f32_bf16<<<768, 256, 0, stream>>>(w_in, w1, (1536 * 512) / 4);
  cvt_f32_bf16<<<256, 256, 0, stream>>>(w_out, w2, (512 * 512) / 4);

  // qkv = x @ W_in^T + b_in; Q scaled 0.125 -> qk, V transposed -> vT
  gemm_bt<1><<<dim3(12, 64), 256, 0, stream>>>(xb, w1, b_in, qk, vT, 8192, 1536, 512);
  attn_fused<<<512, 512, 0, stream>>>(qk, vT, gb, bstr, attn_buf);
  // out = attn @ W_out^T + b_out, fp32
  gemm_bt<0><<<dim3(4, 64), 256, 0, stream>>>(attn_buf, w2, b_out, d_out, nullptr, 8192, 512, 512);
}

// Round 4
// 159.343 us; speedup vs baseline: 1.0578x; 1.0578x over previous
//
#include <hip/hip_runtime.h>

typedef __attribute__((ext_vector_type(8))) __bf16 bf16x8;
typedef __attribute__((ext_vector_type(4))) __bf16 bf16x4;
typedef __attribute__((ext_vector_type(4))) float f32x4;

__device__ __forceinline__ void async_load16(const void* g, void* l) {
  __builtin_amdgcn_global_load_lds(
      (const __attribute__((address_space(1))) void*)g,
      (__attribute__((address_space(3))) void*)l, 16, 0, 0);
}

// ---------------- fp32 -> bf16 convert (vectorized) ----------------
__global__ void cvt_f32_bf16(const float* __restrict__ in,
                             __bf16* __restrict__ out, int n4) {
  int i = blockIdx.x * blockDim.x + threadIdx.x;
  int stride = gridDim.x * blockDim.x;
  for (; i < n4; i += stride) {
    float4 v = ((const float4*)in)[i];
    bf16x4 o;
    o[0] = (__bf16)v.x; o[1] = (__bf16)v.y; o[2] = (__bf16)v.z; o[3] = (__bf16)v.w;
    ((bf16x4*)out)[i] = o;
  }
}

// ---------------- C = (A @ Bm^T + bias) [*scale] ----------------
// MODE 0: fp32 out, row stride N.
// MODE 1 (QKV): cols<512 -> qk bf16 (scaled 0.125); 512..1023 -> qk bf16;
//               >=1024 -> vT[b*8+h][d][k] transposed bf16.
template <int MODE>
__global__ __launch_bounds__(256) void gemm_bt(
    const __bf16* __restrict__ A,   // [M][K]
    const __bf16* __restrict__ Bm,  // [N][K]
    const float* __restrict__ bias, // [N]
    void* __restrict__ C0,
    __bf16* __restrict__ vT,
    int M, int N, int K) {
  __shared__ __align__(16) char smem[32768];
  char* lA = smem;
  char* lB = smem + 16384;
  const int t = threadIdx.x;
  const int lane = t & 63;
  const int wid = t >> 6;
  const int wm = wid >> 1, wn = wid & 1;
  const int g = lane >> 4, ln = lane & 15;
  const int m0 = blockIdx.y * 128;
  const int n0 = blockIdx.x * 128;

  const int srow = t >> 3;
  const int sswz = ((t & 7) * 16) ^ ((srow & 7) << 4);
  const size_t KB = (size_t)K * 2;
  const char* gA = (const char*)A + (size_t)m0 * KB;
  const char* gB = (const char*)Bm + (size_t)n0 * KB;

  f32x4 acc[4][4] = {};

  for (int k0 = 0; k0 < K; k0 += 64) {
    __syncthreads();
#pragma unroll
    for (int c = 0; c < 4; ++c) {
      int row = srow + 32 * c;
      async_load16(gA + (size_t)row * KB + k0 * 2 + sswz, lA + c * 4096 + t * 16);
      async_load16(gB + (size_t)row * KB + k0 * 2 + sswz, lB + c * 4096 + t * 16);
    }
    __syncthreads();
#pragma unroll
    for (int ks = 0; ks < 2; ++ks) {
      bf16x8 af[4], bf[4];
#pragma unroll
      for (int i = 0; i < 4; ++i) {
        int ar = wm * 64 + i * 16 + ln;
        int byo = (ks * 64 + g * 16) ^ ((ar & 7) << 4);
        af[i] = *(const bf16x8*)(lA + ar * 128 + byo);
        int br = wn * 64 + i * 16 + ln;
        bf[i] = *(const bf16x8*)(lB + br * 128 + byo);
      }
#pragma unroll
      for (int i = 0; i < 4; ++i)
#pragma unroll
        for (int j = 0; j < 4; ++j)
          acc[i][j] = __builtin_amdgcn_mfma_f32_16x16x32_bf16(af[i], bf[j], acc[i][j], 0, 0, 0);
    }
  }

#pragma unroll
  for (int j = 0; j < 4; ++j) {
    int col = n0 + wn * 64 + j * 16 + ln;
    float bv = bias[col];
    if (MODE == 0) {
#pragma unroll
      for (int i = 0; i < 4; ++i) {
        int row0 = m0 + wm * 64 + i * 16 + g * 4;
#pragma unroll
        for (int r = 0; r < 4; ++r)
          ((float*)C0)[(size_t)(row0 + r) * N + col] = acc[i][j][r] + bv;
      }
    } else if (col < 1024) {
      float scale = (col < 512) ? 0.125f : 1.0f;
#pragma unroll
      for (int i = 0; i < 4; ++i) {
        int row0 = m0 + wm * 64 + i * 16 + g * 4;
#pragma unroll
        for (int r = 0; r < 4; ++r)
          ((__bf16*)C0)[(size_t)(row0 + r) * 1024 + col] = (__bf16)((acc[i][j][r] + bv) * scale);
      }
    } else {
      int h = (col - 1024) >> 6;
      int d = (col - 1024) & 63;
#pragma unroll
      for (int i = 0; i < 4; ++i) {
        int row0 = m0 + wm * 64 + i * 16 + g * 4;
        int b = row0 >> 10;
        bf16x4 pk;
#pragma unroll
        for (int r = 0; r < 4; ++r) pk[r] = (__bf16)(acc[i][j][r] + bv);
        *(bf16x4*)(vT + (((size_t)b * 8 + h) * 64 + d) * 1024 + (row0 & 1023)) = pk;
      }
    }
  }
}

// ---------------- fused flash attention, ZERO barriers ----------------
// 512 blocks (XCD-swizzled), 512 threads = 8 waves = 8 heads. QT=16, KT=32.
// All LDS strictly wave-private (K/V tiles); bias in registers, prefetched
// one tile ahead. LDS 64KB -> 2 blocks/CU (16 waves/CU, 4/SIMD).
__global__ __launch_bounds__(512, 4) void attn_fused(
    const __bf16* __restrict__ qk,   // [B][N][1024]: q(prescaled)|k
    const __bf16* __restrict__ vT,   // [B*8][64 d][1024 k]
    const float* __restrict__ gbias, // [B][N][N]
    const float* __restrict__ bstr,  // [1]
    __bf16* __restrict__ attn) {     // [B][N][512]
  __shared__ __align__(16) char smem[65536];
  const int t = threadIdx.x;
  const int lane = t & 63;
  const int h = t >> 6;
  const int g = lane >> 4, ln = lane & 15;
  const int wg = ((blockIdx.x & 7) << 6) + (blockIdx.x >> 3);
  const int b = wg >> 6;
  const int q0 = (wg & 63) << 4;

  char* Ks = smem + h * 8192;  // [32 k][128B] XOR-swizzled rows (wave-private)
  char* Ps = Ks;               // alias: P[16 q][64B] overwrites K after QK^T
  char* Vs = Ks + 4096;        // [64 d][64B] XOR-swizzled rows (wave-private)

  const float alpha = 1.f / (1.f + __expf(-bstr[0]));
  const float bscale = 10.f * alpha;
  const f32x4 fzero = {0.f, 0.f, 0.f, 0.f};

  // Q A-frags: row = ln, k-dim = ks*32 + g*8 + j (prescaled by 1/8)
  bf16x8 qf[2];
#pragma unroll
  for (int ks = 0; ks < 2; ++ks)
    qf[ks] = *(const bf16x8*)(qk + ((size_t)b * 1024 + q0 + ln) * 1024 +
                              h * 64 + ks * 32 + g * 8);

  float m_run[4], l_run[4];
  f32x4 o_acc[4] = {};
#pragma unroll
  for (int r = 0; r < 4; ++r) { m_run[r] = -1e30f; l_run[r] = 0.f; }

  const int krow = lane >> 3;
  const int ksrc = ((lane & 7) * 16) ^ (krow << 4);
  const int vrow = lane >> 2;
  const int vsrc = ((lane & 3) * 16) ^ ((vrow & 3) << 4);

  const char* qkb = (const char*)qk + (size_t)b * 1024 * 2048;
  const char* vTb = (const char*)vT + (size_t)(b * 8 + h) * 64 * 2048;
  const float* gbb = gbias + (size_t)b * 1024 * 1024 + q0;

  // bias prefetch for tile 0: bpf[ni*4+r] = gbias[b][16ni+ln][q0+4g+r]
  float bpf[8];
#pragma unroll
  for (int ni = 0; ni < 2; ++ni)
#pragma unroll
    for (int r = 0; r < 4; ++r)
      bpf[ni * 4 + r] = gbb[(size_t)(ni * 16 + ln) * 1024 + g * 4 + r];

  // stage tile 0 (wave-private K/V)
#pragma unroll
  for (int c = 0; c < 4; ++c) {
    async_load16(qkb + (size_t)(c * 8 + krow) * 2048 + 1024 + h * 128 + ksrc,
                 Ks + c * 1024 + lane * 16);
    async_load16(vTb + (size_t)(c * 16 + vrow) * 2048 + vsrc,
                 Vs + c * 1024 + lane * 16);
  }

  for (int kt = 0; kt < 32; ++kt) {
    const int k0 = kt * 32;
    // wait staged K/V (and last tile's bias regs); issued >= 1 iteration ago
    asm volatile("s_waitcnt vmcnt(0)" ::: "memory");
    __builtin_amdgcn_sched_barrier(0);

    // bias for current tile (sigmoid recomputed per head; VALU has headroom)
    float bias_cur[8];
#pragma unroll
    for (int i = 0; i < 8; ++i)
      bias_cur[i] = bscale * (1.f / (1.f + __expf(-bpf[i])) - 0.5f);
    // prefetch next tile's bias into registers (HBM latency hidden)
    if (kt < 31) {
#pragma unroll
      for (int ni = 0; ni < 2; ++ni)
#pragma unroll
        for (int r = 0; r < 4; ++r)
          bpf[ni * 4 + r] =
              gbb[(size_t)(k0 + 32 + ni * 16 + ln) * 1024 + g * 4 + r];
    }

    // S = Q K^T  (D: q = 4g + r, key = ni*16 + ln)
    f32x4 s[2];
#pragma unroll
    for (int ni = 0; ni < 2; ++ni) {
      int br = ni * 16 + ln;
      int sw = (br & 7) << 4;
#pragma unroll
      for (int ks = 0; ks < 2; ++ks) {
        bf16x8 kf = *(const bf16x8*)(Ks + br * 128 + ((ks * 64 + g * 16) ^ sw));
        s[ni] = __builtin_amdgcn_mfma_f32_16x16x32_bf16(
            qf[ks], kf, (ks == 0) ? fzero : s[ni], 0, 0, 0);
      }
#pragma unroll
      for (int r = 0; r < 4; ++r)
        s[ni][r] += bias_cur[ni * 4 + r];
    }

    // online softmax (rows spread over the 16 ln-lanes)
#pragma unroll
    for (int r = 0; r < 4; ++r) {
      float tm = fmaxf(s[0][r], s[1][r]);
#pragma unroll
      for (int off = 1; off < 16; off <<= 1)
        tm = fmaxf(tm, __shfl_xor(tm, off, 64));
      float newm = fmaxf(m_run[r], tm);
      float corr = __expf(m_run[r] - newm);
      float p0 = __expf(s[0][r] - newm);
      float p1 = __expf(s[1][r] - newm);
      s[0][r] = p0; s[1][r] = p1;
      float rs = p0 + p1;
#pragma unroll
      for (int off = 1; off < 16; off <<= 1)
        rs += __shfl_xor(rs, off, 64);
      m_run[r] = newm;
      l_run[r] = l_run[r] * corr + rs;
#pragma unroll
      for (int di = 0; di < 4; ++di)
        o_acc[di][r] *= corr;
    }

    // P -> LDS bf16 (swizzled), wave-local overwrite of K region
#pragma unroll
    for (int ni = 0; ni < 2; ++ni)
#pragma unroll
      for (int r = 0; r < 4; ++r) {
        int q = g * 4 + r;
        *(__bf16*)(Ps + q * 64 + ((ni * 32 + ln * 2) ^ (((q >> 1) & 3) << 4))) =
            (__bf16)s[ni][r];
      }

    // O += P V : both operands via swizzled ds_read_b128
    bf16x8 pf = *(const bf16x8*)(Ps + ln * 64 + ((g * 16) ^ (((ln >> 1) & 3) << 4)));
#pragma unroll
    for (int di = 0; di < 4; ++di) {
      bf16x8 vf = *(const bf16x8*)(Vs + (di * 16 + ln) * 64 + ((g * 16) ^ ((ln & 3) << 4)));
      o_acc[di] = __builtin_amdgcn_mfma_f32_16x16x32_bf16(pf, vf, o_acc[di], 0, 0, 0);
    }

    // stage next tile at iteration end: all LDS reads above have retired
    // (compiler's lgkmcnt(0) precedes the PV MFMAs), so overwrite is safe.
    if (kt < 31) {
      const int k1 = k0 + 32;
#pragma unroll
      for (int c = 0; c < 4; ++c) {
        async_load16(qkb + (size_t)(k1 + c * 8 + krow) * 2048 + 1024 + h * 128 + ksrc,
                     Ks + c * 1024 + lane * 16);
        async_load16(vTb + (size_t)(c * 16 + vrow) * 2048 + (size_t)k1 * 2 + vsrc,
                     Vs + c * 1024 + lane * 16);
      }
    }
  }

  // normalize + store (attn[b][q][h*64 + di*16 + ln]); D row = 4g + r
#pragma unroll
  for (int r = 0; r < 4; ++r) {
    float inv = 1.f / l_run[r];
    int q = q0 + g * 4 + r;
#pragma unroll
    for (int di = 0; di < 4; ++di)
      attn[((size_t)b * 1024 + q) * 512 + h * 64 + di * 16 + ln] =
          (__bf16)(o_acc[di][r] * inv);
  }
}

extern "C" void kernel_launch(void* const* d_in, const int* in_sizes, int n_in,
                              void* d_out, int out_size, void* d_ws, size_t ws_size,
                              hipStream_t stream) {
  const float* x     = (const float*)d_in[0];
  const float* gb    = (const float*)d_in[1];
  const float* w_in  = (const float*)d_in[2];
  const float* b_in  = (const float*)d_in[3];
  const float* w_out = (const float*)d_in[4];
  const float* b_out = (const float*)d_in[5];
  const float* bstr  = (const float*)d_in[6];

  char* ws = (char*)d_ws;
  __bf16* qk  = (__bf16*)(ws);                        // 16777216 B
  __bf16* vT  = (__bf16*)(ws + 16777216);             // 8388608 B
  __bf16* xb  = (__bf16*)(ws + 25165824);             // 8388608 B
  __bf16* w1  = (__bf16*)(ws + 33554432);             // 1572864 B
  __bf16* w2  = (__bf16*)(ws + 35127296);             // 524288 B
  __bf16* attn_buf = xb;  // alias: x_bf16 dead after GEMM1

  cvt_f32_bf16<<<2048, 256, 0, stream>>>(x, xb, (8 * 1024 * 512) / 4);
  cvt_f32_bf16<<<768, 256, 0, stream>>>(w_in, w1, (1536 * 512) / 4);
  cvt_f32_bf16<<<256, 256, 0, stream>>>(w_out, w2, (512 * 512) / 4);

  gemm_bt<1><<<dim3(12, 64), 256, 0, stream>>>(xb, w1, b_in, qk, vT, 8192, 1536, 512);
  attn_fused<<<512, 512, 0, stream>>>(qk, vT, gb, bstr, attn_buf);
  gemm_bt<0><<<dim3(4, 64), 256, 0, stream>>>(attn_buf, w2, b_out, d_out, nullptr, 8192, 512, 512);
}